// Round 1
// baseline (10457.500 us; speedup 1.0000x reference)
//
#include <hip/hip_runtime.h>
#include <cstdint>

#define DIM   1024
#define BATCH 4
#define SEQ   4096
#define E3    3072
#define MTOT  (BATCH*SEQ)   // 16384 rows

// ---------------------------------------------------------------------------
// Kernel 1: fused QKV projection (fp32 GEMM)
//   C[m,e] = sum_d X[m,d]*W[e,d] + b[e],  M=16384, N=3072, K=1024
//   e in [0,1024)    -> Q[b][s][d]        (row-major)
//   e in [1024,2048) -> Kt4 packed [b][d>>2][s][d&3]: lets the attention
//                       kernel load K with lane=key, float4 over d (coalesced)
//   e in [2048,3072) -> V[b][s][d]        (row-major)
// 64x64 tile, 256 threads, 4x4 micro-tile, K-chunk 16.
// ---------------------------------------------------------------------------
__global__ __launch_bounds__(256)
void qkv_gemm(const float* __restrict__ X, const float* __restrict__ W,
              const float* __restrict__ bias,
              float* __restrict__ Qb, float* __restrict__ Kt4,
              float* __restrict__ Vb)
{
    __shared__ float As[16][68];   // [k][m], pad 68 to break conflicts
    __shared__ float Bs[16][68];   // [k][e]
    const int t  = threadIdx.x;
    const int e0 = blockIdx.x * 64;
    const int m0 = blockIdx.y * 64;
    const int tx = t & 15, ty = t >> 4;
    const int lm = t >> 2;          // 0..63 : row within tile for staging
    const int kg = (t & 3) * 4;     // 0,4,8,12 : k-subchunk for staging

    float acc[4][4] = {};
    for (int k0 = 0; k0 < DIM; k0 += 16) {
        float4 av = *(const float4*)&X[(size_t)(m0 + lm)*DIM + k0 + kg];
        float4 bv = *(const float4*)&W[(size_t)(e0 + lm)*DIM + k0 + kg];
        __syncthreads();
        As[kg+0][lm]=av.x; As[kg+1][lm]=av.y; As[kg+2][lm]=av.z; As[kg+3][lm]=av.w;
        Bs[kg+0][lm]=bv.x; Bs[kg+1][lm]=bv.y; Bs[kg+2][lm]=bv.z; Bs[kg+3][lm]=bv.w;
        __syncthreads();
        #pragma unroll
        for (int kk = 0; kk < 16; ++kk) {
            float4 a4 = *(const float4*)&As[kk][ty*4];
            float4 b4 = *(const float4*)&Bs[kk][tx*4];
            float a[4]  = {a4.x, a4.y, a4.z, a4.w};
            float bb[4] = {b4.x, b4.y, b4.z, b4.w};
            #pragma unroll
            for (int i = 0; i < 4; ++i)
                #pragma unroll
                for (int j = 0; j < 4; ++j)
                    acc[i][j] += a[i]*bb[j];
        }
    }

    float4 bia = *(const float4*)&bias[e0 + tx*4];
    float bj[4] = {bia.x, bia.y, bia.z, bia.w};
    const int region = e0 >> 10;   // tile is entirely inside Q, K, or V slab
    #pragma unroll
    for (int i = 0; i < 4; ++i) {
        int mg = m0 + ty*4 + i;
        int bi = mg >> 12;          // / SEQ
        int si = mg & (SEQ-1);
        float4 c;
        c.x = acc[i][0]+bj[0]; c.y = acc[i][1]+bj[1];
        c.z = acc[i][2]+bj[2]; c.w = acc[i][3]+bj[3];
        if (region == 0) {
            *(float4*)&Qb[((size_t)bi*SEQ + si)*DIM + e0 + tx*4] = c;
        } else if (region == 1) {
            int d = e0 - 1024 + tx*4;   // thread owns 4 consecutive d
            *(float4*)&Kt4[(((size_t)bi*256 + (d>>2))*SEQ + si)*4] = c;
        } else {
            int d = e0 - 2048 + tx*4;
            *(float4*)&Vb[((size_t)bi*SEQ + si)*DIM + d] = c;
        }
    }
}

// ---------------------------------------------------------------------------
// Kernel 2: flash attention, fp32 vector ALU, online softmax.
// Block = 256 threads handles TQ=8 query rows of one batch.
// K-tiles of TK=512 keys: each thread computes scores for 2 keys (full
// D=1024 dot against 8 LDS-resident Q rows), then online-softmax rescale,
// then PV accumulation with threads over d (thread t owns d = 4t..4t+3).
// ---------------------------------------------------------------------------
#define TQ 8
#define TK 512

__global__ __launch_bounds__(256)
void flash_attn(const float* __restrict__ Qb, const float* __restrict__ Kt4,
                const float* __restrict__ Vb, float* __restrict__ out)
{
    __shared__ float Qs[TQ*DIM];       // 32 KB
    __shared__ float ps[TQ][TK];       // 16 KB
    __shared__ float wred[2][TQ][4];   // per-wave max / sum
    const int t    = threadIdx.x;
    const int b    = blockIdx.y;
    const int q0   = blockIdx.x * TQ;
    const int lane = t & 63, w = t >> 6;

    for (int i = t*4; i < TQ*DIM; i += 1024) {
        int ql = i >> 10, d = i & (DIM-1);
        *(float4*)&Qs[i] = *(const float4*)&Qb[((size_t)b*SEQ + q0 + ql)*DIM + d];
    }
    __syncthreads();

    float O[TQ][4] = {};
    float mrow[TQ], lrow[TQ];
    #pragma unroll
    for (int q = 0; q < TQ; ++q) { mrow[q] = -1e30f; lrow[q] = 0.f; }
    const float scale = 0.03125f;   // 1/sqrt(1024)

    for (int k0 = 0; k0 < SEQ; k0 += TK) {
        // ---- Phase A: scores for 2 keys/thread over all 8 q rows ----
        float s0[TQ] = {}, s1[TQ] = {};
        const float* kp1 = &Kt4[((size_t)b*256*SEQ + (size_t)(k0 + t))*4];
        const float* kp2 = kp1 + 256*4;
        #pragma unroll 2
        for (int d4 = 0; d4 < DIM/4; ++d4) {
            float4 kv1 = *(const float4*)&kp1[(size_t)d4*SEQ*4];
            float4 kv2 = *(const float4*)&kp2[(size_t)d4*SEQ*4];
            #pragma unroll
            for (int q = 0; q < TQ; ++q) {
                float4 qv = *(const float4*)&Qs[q*DIM + d4*4];
                s0[q] += qv.x*kv1.x; s0[q] += qv.y*kv1.y;
                s0[q] += qv.z*kv1.z; s0[q] += qv.w*kv1.w;
                s1[q] += qv.x*kv2.x; s1[q] += qv.y*kv2.y;
                s1[q] += qv.z*kv2.z; s1[q] += qv.w*kv2.w;
            }
        }
        // ---- online softmax bookkeeping ----
        float tm[TQ];
        #pragma unroll
        for (int q = 0; q < TQ; ++q) {
            s0[q] *= scale; s1[q] *= scale;
            tm[q] = fmaxf(s0[q], s1[q]);
        }
        #pragma unroll
        for (int q = 0; q < TQ; ++q)
            for (int off = 32; off; off >>= 1)
                tm[q] = fmaxf(tm[q], __shfl_xor(tm[q], off, 64));
        if (lane == 0) {
            #pragma unroll
            for (int q = 0; q < TQ; ++q) wred[0][q][w] = tm[q];
        }
        __syncthreads();
        float alpha[TQ], psum[TQ];
        #pragma unroll
        for (int q = 0; q < TQ; ++q) {
            float mt = fmaxf(fmaxf(wred[0][q][0], wred[0][q][1]),
                             fmaxf(wred[0][q][2], wred[0][q][3]));
            float m_new = fmaxf(mrow[q], mt);
            alpha[q] = __expf(mrow[q] - m_new);
            float p0 = __expf(s0[q] - m_new);
            float p1 = __expf(s1[q] - m_new);
            ps[q][t]       = p0;
            ps[q][256 + t] = p1;
            psum[q] = p0 + p1;
            mrow[q] = m_new;
        }
        #pragma unroll
        for (int q = 0; q < TQ; ++q)
            for (int off = 32; off; off >>= 1)
                psum[q] += __shfl_xor(psum[q], off, 64);
        if (lane == 0) {
            #pragma unroll
            for (int q = 0; q < TQ; ++q) wred[1][q][w] = psum[q];
        }
        __syncthreads();
        #pragma unroll
        for (int q = 0; q < TQ; ++q) {
            lrow[q] = lrow[q]*alpha[q]
                    + (wred[1][q][0]+wred[1][q][1]+wred[1][q][2]+wred[1][q][3]);
            O[q][0] *= alpha[q]; O[q][1] *= alpha[q];
            O[q][2] *= alpha[q]; O[q][3] *= alpha[q];
        }
        // ---- Phase B: O += P * V, thread t owns d = 4t..4t+3 ----
        const float* vp = &Vb[((size_t)b*SEQ + k0)*DIM + t*4];
        for (int kk = 0; kk < TK; kk += 4) {
            float4 v0 = *(const float4*)&vp[(size_t)(kk+0)*DIM];
            float4 v1 = *(const float4*)&vp[(size_t)(kk+1)*DIM];
            float4 v2 = *(const float4*)&vp[(size_t)(kk+2)*DIM];
            float4 v3 = *(const float4*)&vp[(size_t)(kk+3)*DIM];
            #pragma unroll
            for (int q = 0; q < TQ; ++q) {
                float4 p4 = *(const float4*)&ps[q][kk];   // broadcast read
                O[q][0] += p4.x*v0.x; O[q][0] += p4.y*v1.x;
                O[q][0] += p4.z*v2.x; O[q][0] += p4.w*v3.x;
                O[q][1] += p4.x*v0.y; O[q][1] += p4.y*v1.y;
                O[q][1] += p4.z*v2.y; O[q][1] += p4.w*v3.y;
                O[q][2] += p4.x*v0.z; O[q][2] += p4.y*v1.z;
                O[q][2] += p4.z*v2.z; O[q][2] += p4.w*v3.z;
                O[q][3] += p4.x*v0.w; O[q][3] += p4.y*v1.w;
                O[q][3] += p4.z*v2.w; O[q][3] += p4.w*v3.w;
            }
        }
        __syncthreads();   // before next tile overwrites ps
    }
    // ---- epilogue ----
    #pragma unroll
    for (int q = 0; q < TQ; ++q) {
        float inv = 1.0f / lrow[q];
        float4 o;
        o.x = O[q][0]*inv; o.y = O[q][1]*inv;
        o.z = O[q][2]*inv; o.w = O[q][3]*inv;
        *(float4*)&out[((size_t)b*SEQ + q0 + q)*DIM + t*4] = o;
    }
}

// ---------------------------------------------------------------------------
extern "C" void kernel_launch(void* const* d_in, const int* in_sizes, int n_in,
                              void* d_out, int out_size, void* d_ws, size_t ws_size,
                              hipStream_t stream) {
    const float* X    = (const float*)d_in[0];   // [4,4096,1024]
    const float* W    = (const float*)d_in[1];   // [3072,1024]
    const float* bias = (const float*)d_in[2];   // [3072]
    float* out = (float*)d_out;

    // workspace: Q (64MB) | Kt4 (64MB) | V (64MB)  = 192MB
    float* Qb  = (float*)d_ws;
    float* Kt4 = Qb  + (size_t)MTOT*DIM;
    float* Vb  = Kt4 + (size_t)MTOT*DIM;

    qkv_gemm<<<dim3(E3/64, MTOT/64), 256, 0, stream>>>(X, W, bias, Qb, Kt4, Vb);
    flash_attn<<<dim3(SEQ/TQ, BATCH), 256, 0, stream>>>(Qb, Kt4, Vb, out);
}

// Round 3
// 2097.062 us; speedup vs baseline: 4.9867x; 4.9867x over previous
//
#include <hip/hip_runtime.h>
#include <cstdint>

typedef unsigned short u16;
typedef __attribute__((ext_vector_type(8))) short bf16x8;
typedef __attribute__((ext_vector_type(4))) float f32x4;
typedef __attribute__((ext_vector_type(4))) unsigned u32x4;

#define DIM   1024
#define BATCH 4
#define SEQ   4096
#define E3    3072
#define MTOT  (BATCH*SEQ)   // 16384

// ---------- bf16 helpers ----------
__device__ __forceinline__ u16 f2bf(float x) {          // RNE
    union { float f; unsigned u; } v; v.f = x;
    unsigned r = v.u + 0x7FFFu + ((v.u >> 16) & 1u);
    return (u16)(r >> 16);
}
__device__ __forceinline__ float bf2f(u16 h) {
    union { unsigned u; float f; } v; v.u = ((unsigned)h) << 16;
    return v.f;
}
__device__ __forceinline__ void split2(float x, u16& hi, u16& lo) {
    u16 h = f2bf(x); hi = h; lo = f2bf(x - bf2f(h));
}
// pack (hi16 of u0, hi16 of u1) -> one u32 (u0 in low half)
__device__ __forceinline__ unsigned hipair(unsigned u0, unsigned u1) {
#if __has_builtin(__builtin_amdgcn_perm)
    return __builtin_amdgcn_perm(u1, u0, 0x07060302u);
#else
    return (u0 >> 16) | (u1 & 0xFFFF0000u);
#endif
}
// 8 fp32 -> bf16 hi + bf16 lo fragments (truncation split; residual ~2^-16)
__device__ __forceinline__ void split8(u32x4 x0, u32x4 x1, bf16x8& hi, bf16x8& lo) {
    union { unsigned u[4]; bf16x8 v; } H, L2;
    H.u[0] = hipair(x0.x, x0.y);
    H.u[1] = hipair(x0.z, x0.w);
    H.u[2] = hipair(x1.x, x1.y);
    H.u[3] = hipair(x1.z, x1.w);
    unsigned r0 = __float_as_uint(__uint_as_float(x0.x) - __uint_as_float(x0.x & 0xFFFF0000u));
    unsigned r1 = __float_as_uint(__uint_as_float(x0.y) - __uint_as_float(x0.y & 0xFFFF0000u));
    unsigned r2 = __float_as_uint(__uint_as_float(x0.z) - __uint_as_float(x0.z & 0xFFFF0000u));
    unsigned r3 = __float_as_uint(__uint_as_float(x0.w) - __uint_as_float(x0.w & 0xFFFF0000u));
    unsigned r4 = __float_as_uint(__uint_as_float(x1.x) - __uint_as_float(x1.x & 0xFFFF0000u));
    unsigned r5 = __float_as_uint(__uint_as_float(x1.y) - __uint_as_float(x1.y & 0xFFFF0000u));
    unsigned r6 = __float_as_uint(__uint_as_float(x1.z) - __uint_as_float(x1.z & 0xFFFF0000u));
    unsigned r7 = __float_as_uint(__uint_as_float(x1.w) - __uint_as_float(x1.w & 0xFFFF0000u));
    L2.u[0] = hipair(r0, r1);
    L2.u[1] = hipair(r2, r3);
    L2.u[2] = hipair(r4, r5);
    L2.u[3] = hipair(r6, r7);
    hi = H.v; lo = L2.v;
}

// ---------- async global->LDS 16B ----------
__device__ __forceinline__ void gl16(const void* g, void* l) {
    __builtin_amdgcn_global_load_lds(
        (const __attribute__((address_space(1))) void*)g,
        (__attribute__((address_space(3))) void*)l, 16, 0, 0);
}

// ---------------------------------------------------------------------------
// Shared split-bf16 GEMM mainloop (both operands pre-split, k-major).
// C[128x128], 256 thr = 4 waves 2x2, wave = 4x4 MFMA 16x16x32 tiles, 3-term.
// LDS fragment-identity chunks: lane L <-> (row L&15, kq L>>4), 16B each.
// ---------------------------------------------------------------------------
__device__ __forceinline__ void gemm_main(
    const u16* __restrict__ Ah, const u16* __restrict__ Al, int sA,
    const u16* __restrict__ Bh, const u16* __restrict__ Bl, int sB,
    int K, int m0, int n0,
    u16* sAh, u16* sAl, u16* sBh, u16* sBl,
    f32x4 acc[4][4])
{
    const int t  = threadIdx.x;
    const int w  = t >> 6, L = t & 63;
    const int rL = L & 15, kq = L >> 4;
    const int c0 = 2*w;

    const size_t a0 = (size_t)(m0 + c0*16      + rL)*sA + kq*8;
    const size_t a1 = (size_t)(m0 + c0*16 + 16 + rL)*sA + kq*8;
    const size_t b0 = (size_t)(n0 + c0*16      + rL)*sB + kq*8;
    const size_t b1 = (size_t)(n0 + c0*16 + 16 + rL)*sB + kq*8;
    u16* lA0  = sAh + c0*512; u16* lA1  = lA0  + 512;
    u16* lAl0 = sAl + c0*512; u16* lAl1 = lAl0 + 512;
    u16* lB0  = sBh + c0*512; u16* lB1  = lB0  + 512;
    u16* lBl0 = sBl + c0*512; u16* lBl1 = lBl0 + 512;

    const int cm = 4*(w>>1), cn = 4*(w&1);

    for (int k0 = 0; k0 < K; k0 += 32) {
        __syncthreads();
        gl16(Ah + a0 + k0, lA0);  gl16(Ah + a1 + k0, lA1);
        gl16(Al + a0 + k0, lAl0); gl16(Al + a1 + k0, lAl1);
        gl16(Bh + b0 + k0, lB0);  gl16(Bh + b1 + k0, lB1);
        gl16(Bl + b0 + k0, lBl0); gl16(Bl + b1 + k0, lBl1);
        __syncthreads();

        bf16x8 ah[4], al[4], bh[4], bl[4];
        #pragma unroll
        for (int i = 0; i < 4; ++i) {
            ah[i] = *(const bf16x8*)&sAh[(cm+i)*512 + L*8];
            al[i] = *(const bf16x8*)&sAl[(cm+i)*512 + L*8];
            bh[i] = *(const bf16x8*)&sBh[(cn+i)*512 + L*8];
            bl[i] = *(const bf16x8*)&sBl[(cn+i)*512 + L*8];
        }
        #pragma unroll
        for (int mt = 0; mt < 4; ++mt)
            #pragma unroll
            for (int nt = 0; nt < 4; ++nt) {
                acc[mt][nt] = __builtin_amdgcn_mfma_f32_16x16x32_bf16(ah[mt], bh[nt], acc[mt][nt], 0,0,0);
                acc[mt][nt] = __builtin_amdgcn_mfma_f32_16x16x32_bf16(ah[mt], bl[nt], acc[mt][nt], 0,0,0);
                acc[mt][nt] = __builtin_amdgcn_mfma_f32_16x16x32_bf16(al[mt], bh[nt], acc[mt][nt], 0,0,0);
            }
    }
}

// ---------------------------------------------------------------------------
// fp32 -> split bf16 (elementwise, RNE), used for W only
// ---------------------------------------------------------------------------
__global__ __launch_bounds__(256)
void split_f32(const float* __restrict__ x, u16* __restrict__ hi, u16* __restrict__ lo) {
    size_t i = ((size_t)blockIdx.x*256 + threadIdx.x)*4;
    float4 v = *(const float4*)&x[i];
    ushort4 h, l;
    split2(v.x, h.x, l.x); split2(v.y, h.y, l.y);
    split2(v.z, h.z, l.z); split2(v.w, h.w, l.w);
    *(ushort4*)&hi[i] = h;
    *(ushort4*)&lo[i] = l;
}

// ---------------------------------------------------------------------------
// QKV GEMM: A = X fp32 (on-the-fly truncation split), B = W pre-split.
// A LDS chunk (16 rows x 32 k fp32 = 2KB): byte = q*512 + half*256 + row*16
//   -> fragment b128 reads are <=2-way bank aliased (free), and staging is
//   expressible as gl16 (lane->global permuted to invert the layout).
// ---------------------------------------------------------------------------
__global__ __launch_bounds__(256,2)
void gemm_qkv(const float* __restrict__ X,
              const u16* __restrict__ Wh, const u16* __restrict__ Wl,
              const float* __restrict__ bias,
              u16* __restrict__ Qh, u16* __restrict__ Ql,
              u16* __restrict__ Kh, u16* __restrict__ Kl,
              u16* __restrict__ Vth, u16* __restrict__ Vtl)
{
    __shared__ __align__(16) float sAf[4096];              // 16 KB
    __shared__ __align__(16) u16 sBh[4096], sBl[4096];     // 8+8 KB
    const int t = threadIdx.x, w = t >> 6, L = t & 63;
    const int m0 = blockIdx.y*128, n0 = blockIdx.x*128;
    const int c0 = 2*w;

    // A staging: call (cc,s): lane L fetches row=L&15, q=2s+(L>>5), half=(L>>4)&1
    const int rowA = L & 15, halfA = (L >> 4) & 1, qA = L >> 5;
    const float* gA[2][2]; float* lA[2][2];
    #pragma unroll
    for (int cc = 0; cc < 2; ++cc)
        #pragma unroll
        for (int s = 0; s < 2; ++s) {
            gA[cc][s] = X + (size_t)(m0 + (c0+cc)*16 + rowA)*DIM + (2*s+qA)*8 + halfA*4;
            lA[cc][s] = sAf + (c0+cc)*512 + s*256;
        }
    // B staging (identity layout)
    const size_t b0 = (size_t)(n0 + c0*16      + (L&15))*DIM + (L>>4)*8;
    const size_t b1 = (size_t)(n0 + c0*16 + 16 + (L&15))*DIM + (L>>4)*8;
    u16* lB0  = sBh + c0*512; u16* lB1  = lB0  + 512;
    u16* lB0l = sBl + c0*512; u16* lB1l = lB0l + 512;

    const int cm = 4*(w>>1), cn = 4*(w&1);
    const int fq = L >> 4, fr = L & 15;
    f32x4 acc[4][4];
    #pragma unroll
    for (int i=0;i<4;++i)
        #pragma unroll
        for (int j=0;j<4;++j) acc[i][j] = (f32x4){0.f,0.f,0.f,0.f};

    for (int k0 = 0; k0 < DIM; k0 += 32) {
        __syncthreads();
        gl16(gA[0][0] + k0, lA[0][0]); gl16(gA[0][1] + k0, lA[0][1]);
        gl16(gA[1][0] + k0, lA[1][0]); gl16(gA[1][1] + k0, lA[1][1]);
        gl16(Wh + b0 + k0, lB0);  gl16(Wh + b1 + k0, lB1);
        gl16(Wl + b0 + k0, lB0l); gl16(Wl + b1 + k0, lB1l);
        __syncthreads();

        bf16x8 ah[4], al[4], bh[4], bl[4];
        #pragma unroll
        for (int i = 0; i < 4; ++i) {
            const float* base = sAf + (cm+i)*512 + fq*128 + fr*4;
            u32x4 x0 = *(const u32x4*)base;
            u32x4 x1 = *(const u32x4*)(base + 64);
            split8(x0, x1, ah[i], al[i]);
            bh[i] = *(const bf16x8*)&sBh[(cn+i)*512 + L*8];
            bl[i] = *(const bf16x8*)&sBl[(cn+i)*512 + L*8];
        }
        #pragma unroll
        for (int mt = 0; mt < 4; ++mt)
            #pragma unroll
            for (int nt = 0; nt < 4; ++nt) {
                acc[mt][nt] = __builtin_amdgcn_mfma_f32_16x16x32_bf16(ah[mt], bh[nt], acc[mt][nt], 0,0,0);
                acc[mt][nt] = __builtin_amdgcn_mfma_f32_16x16x32_bf16(ah[mt], bl[nt], acc[mt][nt], 0,0,0);
                acc[mt][nt] = __builtin_amdgcn_mfma_f32_16x16x32_bf16(al[mt], bh[nt], acc[mt][nt], 0,0,0);
            }
    }

    const int wm = 64*(w>>1), wn = 64*(w&1);
    const int cl = L&15, rq = (L>>4)*4;
    #pragma unroll
    for (int nt = 0; nt < 4; ++nt) {
        int col = n0 + wn + nt*16 + cl;
        float bc = bias[col];
        int reg = col >> 10, d = col & (DIM-1);
        #pragma unroll
        for (int mt = 0; mt < 4; ++mt) {
            int row0 = m0 + wm + mt*16 + rq;
            int bi = row0 >> 12, s0 = row0 & (SEQ-1);
            if (reg == 0) {
                #pragma unroll
                for (int r = 0; r < 4; ++r) {
                    u16 h,l; split2(acc[mt][nt][r] + bc, h, l);
                    size_t idx = ((size_t)bi*SEQ + s0 + r)*DIM + d;
                    Qh[idx] = h; Ql[idx] = l;
                }
            } else if (reg == 1) {
                #pragma unroll
                for (int r = 0; r < 4; ++r) {
                    u16 h,l; split2(acc[mt][nt][r] + bc, h, l);
                    size_t idx = ((size_t)bi*SEQ + s0 + r)*DIM + d;
                    Kh[idx] = h; Kl[idx] = l;
                }
            } else {
                ushort4 hv, lv;
                split2(acc[mt][nt][0] + bc, hv.x, lv.x);
                split2(acc[mt][nt][1] + bc, hv.y, lv.y);
                split2(acc[mt][nt][2] + bc, hv.z, lv.z);
                split2(acc[mt][nt][3] + bc, hv.w, lv.w);
                size_t base = ((size_t)bi*DIM + d)*SEQ + s0;
                *(ushort4*)&Vth[base] = hv;
                *(ushort4*)&Vtl[base] = lv;
            }
        }
    }
}

// ---------------------------------------------------------------------------
// Scores GEMM (per batch): S = scale * Qsplit @ Ksplit^T  -> d_out (fp32)
// ---------------------------------------------------------------------------
__global__ __launch_bounds__(256,2)
void gemm_scores(const u16* __restrict__ Qh, const u16* __restrict__ Ql,
                 const u16* __restrict__ Kh, const u16* __restrict__ Kl,
                 float* __restrict__ S)
{
    __shared__ __align__(16) u16 sAh[4096], sAl[4096], sBh[4096], sBl[4096];
    f32x4 acc[4][4];
    #pragma unroll
    for (int i=0;i<4;++i)
        #pragma unroll
        for (int j=0;j<4;++j) acc[i][j] = (f32x4){0.f,0.f,0.f,0.f};

    const int m0 = blockIdx.y*128, n0 = blockIdx.x*128;
    gemm_main(Qh, Ql, DIM, Kh, Kl, DIM, DIM, m0, n0, sAh,sAl,sBh,sBl, acc);

    const int t = threadIdx.x, w = t>>6, L = t&63;
    const int wm = 64*(w>>1), wn = 64*(w&1);
    const int cl = L&15, rq = (L>>4)*4;
    const float scale = 0.03125f;
    #pragma unroll
    for (int nt = 0; nt < 4; ++nt) {
        int col = n0 + wn + nt*16 + cl;
        #pragma unroll
        for (int mt = 0; mt < 4; ++mt) {
            int row0 = m0 + wm + mt*16 + rq;
            #pragma unroll
            for (int r = 0; r < 4; ++r)
                S[(size_t)(row0 + r)*SEQ + col] = acc[mt][nt][r]*scale;
        }
    }
}

// ---------------------------------------------------------------------------
// Row softmax over S, packing P split-bf16 in place: row = [4096 hi][4096 lo]
// ---------------------------------------------------------------------------
__global__ __launch_bounds__(256)
void softmax_pack(float* __restrict__ S)
{
    __shared__ float red[4];
    const int t = threadIdx.x, L = t & 63, w = t >> 6;
    float* Srow = S + (size_t)blockIdx.x*SEQ;

    float v[16];
    float m = -1e30f;
    #pragma unroll
    for (int j = 0; j < 4; ++j) {
        float4 x = *(const float4*)&Srow[t*4 + j*1024];
        v[4*j+0]=x.x; v[4*j+1]=x.y; v[4*j+2]=x.z; v[4*j+3]=x.w;
        m = fmaxf(m, fmaxf(fmaxf(x.x,x.y), fmaxf(x.z,x.w)));
    }
    #pragma unroll
    for (int off = 32; off; off >>= 1) m = fmaxf(m, __shfl_xor(m, off, 64));
    if (L == 0) red[w] = m;
    __syncthreads();
    m = fmaxf(fmaxf(red[0],red[1]), fmaxf(red[2],red[3]));

    float s = 0.f;
    #pragma unroll
    for (int i = 0; i < 16; ++i) { v[i] = __expf(v[i] - m); s += v[i]; }
    #pragma unroll
    for (int off = 32; off; off >>= 1) s += __shfl_xor(s, off, 64);
    __syncthreads();
    if (L == 0) red[w] = s;
    __syncthreads();
    s = red[0]+red[1]+red[2]+red[3];
    const float inv = 1.0f / s;

    u16* P = (u16*)Srow;
    #pragma unroll
    for (int j = 0; j < 4; ++j) {
        ushort4 h, l;
        split2(v[4*j+0]*inv, h.x, l.x);
        split2(v[4*j+1]*inv, h.y, l.y);
        split2(v[4*j+2]*inv, h.z, l.z);
        split2(v[4*j+3]*inv, h.w, l.w);
        *(ushort4*)&P[t*4 + j*1024]        = h;
        *(ushort4*)&P[SEQ + t*4 + j*1024]  = l;
    }
}

// ---------------------------------------------------------------------------
// PV GEMM (per batch): O = Psplit @ Vtsplit^T; O rows<2048 -> O0, else O1
// ---------------------------------------------------------------------------
__global__ __launch_bounds__(256,2)
void gemm_pv(const u16* __restrict__ Ph,
             const u16* __restrict__ Vth, const u16* __restrict__ Vtl,
             float* __restrict__ O0, float* __restrict__ O1)
{
    __shared__ __align__(16) u16 sAh[4096], sAl[4096], sBh[4096], sBl[4096];
    f32x4 acc[4][4];
    #pragma unroll
    for (int i=0;i<4;++i)
        #pragma unroll
        for (int j=0;j<4;++j) acc[i][j] = (f32x4){0.f,0.f,0.f,0.f};

    const int m0 = blockIdx.y*128, n0 = blockIdx.x*128;
    gemm_main(Ph, Ph + SEQ, 2*SEQ, Vth, Vtl, SEQ, SEQ, m0, n0, sAh,sAl,sBh,sBl, acc);

    float* obase = (m0 < 2048) ? O0 : O1;
    const int t = threadIdx.x, w = t>>6, L = t&63;
    const int wm = 64*(w>>1), wn = 64*(w&1);
    const int cl = L&15, rq = (L>>4)*4;
    #pragma unroll
    for (int nt = 0; nt < 4; ++nt) {
        int col = n0 + wn + nt*16 + cl;
        #pragma unroll
        for (int mt = 0; mt < 4; ++mt) {
            int row0 = (m0 + wm + mt*16 + rq) & 2047;
            #pragma unroll
            for (int r = 0; r < 4; ++r)
                obase[(size_t)(row0 + r)*DIM + col] = acc[mt][nt][r];
        }
    }
}

// ---------------------------------------------------------------------------
// gather O pieces (in dead Q slots) -> d_out
// ---------------------------------------------------------------------------
__global__ __launch_bounds__(256)
void copy_out(const float* __restrict__ src, float* __restrict__ dst)
{
    const size_t P0 = (size_t)1 << 21;   // piece size in floats (8 MB)
    size_t i = ((size_t)blockIdx.x*256 + threadIdx.x)*4;
    size_t b = i >> 22, rem = i & (((size_t)1<<22)-1);
    size_t off = (rem < P0) ? (b*P0 + rem) : (4*P0 + b*P0 + (rem - P0));
    *(float4*)&dst[i] = *(const float4*)&src[off];
}

// ---------------------------------------------------------------------------
extern "C" void kernel_launch(void* const* d_in, const int* in_sizes, int n_in,
                              void* d_out, int out_size, void* d_ws, size_t ws_size,
                              hipStream_t stream) {
    const float* X    = (const float*)d_in[0];
    const float* W    = (const float*)d_in[1];
    const float* bias = (const float*)d_in[2];
    float* out = (float*)d_out;

    const size_t MB = (size_t)1 << 20;
    if (ws_size < 192*MB) return;   // fail validation loudly instead of faulting
    char* ws = (char*)d_ws;
    // ws (192 MB): Qh Ql Kh Kl Vth Vtl, 32 MB each
    u16* Qh  = (u16*)ws;
    u16* Ql  = (u16*)(ws + 32*MB);
    u16* Kh  = (u16*)(ws + 64*MB);
    u16* Kl  = (u16*)(ws + 96*MB);
    u16* Vth = (u16*)(ws + 128*MB);
    u16* Vtl = (u16*)(ws + 160*MB);
    // d_out doubles as scratch: W split (12 MB) during QKV, then S/P (64 MB)
    u16*  Wh = (u16*)d_out;
    u16*  Wl = (u16*)((char*)d_out + 6*MB);
    float* S = (float*)d_out;

    split_f32<<<E3*DIM/1024, 256, 0, stream>>>(W, Wh, Wl);
    gemm_qkv<<<dim3(E3/128, MTOT/128), 256, 0, stream>>>(
        X, Wh, Wl, bias, Qh, Ql, Kh, Kl, Vth, Vtl);

    for (int b = 0; b < BATCH; ++b) {
        const size_t qo = (size_t)b*SEQ*DIM;
        gemm_scores<<<dim3(SEQ/128, SEQ/128), 256, 0, stream>>>(
            Qh + qo, Ql + qo, Kh + qo, Kl + qo, S);
        softmax_pack<<<SEQ, 256, 0, stream>>>(S);
        gemm_pv<<<dim3(DIM/128, SEQ/128), 256, 0, stream>>>(
            (const u16*)S, Vth + qo, Vtl + qo,
            (float*)(ws + (size_t)b*8*MB),            // O rows 0..2047  (Qh[b] slot)
            (float*)(ws + 32*MB + (size_t)b*8*MB));   // O rows 2048..4095 (Ql[b] slot)
    }
    copy_out<<<MTOT*DIM/1024, 256, 0, stream>>>((const float*)ws, out);
}

// Round 4
// 1290.026 us; speedup vs baseline: 8.1064x; 1.6256x over previous
//
#include <hip/hip_runtime.h>
#include <cstdint>

typedef unsigned short u16;
typedef __attribute__((ext_vector_type(8))) short bf16x8;
typedef __attribute__((ext_vector_type(4))) float f32x4;

#define DIM   1024
#define BATCH 4
#define SEQ   4096
#define E3    3072
#define MTOT  (BATCH*SEQ)   // 16384

// ---------- bf16 helpers (RNE) ----------
__device__ __forceinline__ u16 f2bf(float x) {
    union { float f; unsigned u; } v; v.f = x;
    unsigned r = v.u + 0x7FFFu + ((v.u >> 16) & 1u);
    return (u16)(r >> 16);
}
__device__ __forceinline__ float bf2f(u16 h) {
    union { unsigned u; float f; } v; v.u = ((unsigned)h) << 16;
    return v.f;
}
__device__ __forceinline__ void split2(float x, u16& hi, u16& lo) {
    u16 h = f2bf(x); hi = h; lo = f2bf(x - bf2f(h));
}

// ---------- async global->LDS 16B ----------
__device__ __forceinline__ void gl16(const void* g, void* l) {
    __builtin_amdgcn_global_load_lds(
        (const __attribute__((address_space(1))) void*)g,
        (__attribute__((address_space(3))) void*)l, 16, 0, 0);
}

// ---------------------------------------------------------------------------
// GEMM mainloop: C[128x128] += A * B^T, A single bf16, B bf16 (optionally
// split hi+lo -> 2 MFMA terms). Both k-major, K mult of 32.
// 256 thr = 4 waves 2x2; wave = 4x4 MFMA 16x16x32 tiles.
// LDS fragment-identity chunks: lane L <-> (row L&15, kq L>>4), 16B each.
// ---------------------------------------------------------------------------
template<bool SPLITB>
__device__ __forceinline__ void gemm_main(
    const u16* __restrict__ Ah, int sA,
    const u16* __restrict__ Bh, const u16* __restrict__ Bl, int sB,
    int K, int m0, int n0,
    u16* sAs, u16* sBh, u16* sBl,
    f32x4 acc[4][4])
{
    const int t  = threadIdx.x;
    const int w  = t >> 6, L = t & 63;
    const int rL = L & 15, kq = L >> 4;
    const int c0 = 2*w;

    const size_t a0 = (size_t)(m0 + c0*16 + rL)*sA + kq*8;
    const size_t a1 = a0 + (size_t)16*sA;
    const size_t b0 = (size_t)(n0 + c0*16 + rL)*sB + kq*8;
    const size_t b1 = b0 + (size_t)16*sB;
    u16* lA0  = sAs + c0*512; u16* lA1  = lA0  + 512;
    u16* lB0  = sBh + c0*512; u16* lB1  = lB0  + 512;
    u16* lB0l = sBl + c0*512; u16* lB1l = lB0l + 512;

    const int cm = 4*(w>>1), cn = 4*(w&1);

    for (int k0 = 0; k0 < K; k0 += 32) {
        __syncthreads();
        gl16(Ah + a0 + k0, lA0); gl16(Ah + a1 + k0, lA1);
        gl16(Bh + b0 + k0, lB0); gl16(Bh + b1 + k0, lB1);
        if (SPLITB) { gl16(Bl + b0 + k0, lB0l); gl16(Bl + b1 + k0, lB1l); }
        __syncthreads();

        bf16x8 av[4], bh[4], bl[4];
        #pragma unroll
        for (int i = 0; i < 4; ++i) {
            av[i] = *(const bf16x8*)&sAs[(cm+i)*512 + L*8];
            bh[i] = *(const bf16x8*)&sBh[(cn+i)*512 + L*8];
            if (SPLITB) bl[i] = *(const bf16x8*)&sBl[(cn+i)*512 + L*8];
        }
        #pragma unroll
        for (int mt = 0; mt < 4; ++mt)
            #pragma unroll
            for (int nt = 0; nt < 4; ++nt) {
                acc[mt][nt] = __builtin_amdgcn_mfma_f32_16x16x32_bf16(av[mt], bh[nt], acc[mt][nt], 0,0,0);
                if (SPLITB)
                    acc[mt][nt] = __builtin_amdgcn_mfma_f32_16x16x32_bf16(av[mt], bl[nt], acc[mt][nt], 0,0,0);
            }
    }
}

// ---------------------------------------------------------------------------
// elementwise: fp32 -> split bf16 (W only)
// ---------------------------------------------------------------------------
__global__ __launch_bounds__(256)
void split_f32(const float* __restrict__ x, u16* __restrict__ hi, u16* __restrict__ lo) {
    size_t i = ((size_t)blockIdx.x*256 + threadIdx.x)*4;
    float4 v = *(const float4*)&x[i];
    ushort4 h, l;
    split2(v.x, h.x, l.x); split2(v.y, h.y, l.y);
    split2(v.z, h.z, l.z); split2(v.w, h.w, l.w);
    *(ushort4*)&hi[i] = h;
    *(ushort4*)&lo[i] = l;
}

// elementwise: fp32 -> bf16 (X)
__global__ __launch_bounds__(256)
void cvt_bf16(const float* __restrict__ x, u16* __restrict__ y) {
    size_t i = ((size_t)blockIdx.x*256 + threadIdx.x)*4;
    float4 v = *(const float4*)&x[i];
    ushort4 h;
    h.x = f2bf(v.x); h.y = f2bf(v.y); h.z = f2bf(v.z); h.w = f2bf(v.w);
    *(ushort4*)&y[i] = h;
}

// ---------------------------------------------------------------------------
// QKV GEMM: A = Xbf (bf16), B = W split (2 terms). Epilogue:
//   e in [0,1024)    -> Qh[b][s][d]  (bf16)
//   e in [1024,2048) -> Kh,Kl[b][s][d] (split)
//   e in [2048,3072) -> Vth[b][d][s] (bf16, transposed)
// ---------------------------------------------------------------------------
__global__ __launch_bounds__(256,3)
void gemm_qkv(const u16* __restrict__ Xbf,
              const u16* __restrict__ Wh, const u16* __restrict__ Wl,
              const float* __restrict__ bias,
              u16* __restrict__ Qh,
              u16* __restrict__ Kh, u16* __restrict__ Kl,
              u16* __restrict__ Vth)
{
    __shared__ __align__(16) u16 sA[4096], sBh[4096], sBl[4096];
    f32x4 acc[4][4];
    #pragma unroll
    for (int i=0;i<4;++i)
        #pragma unroll
        for (int j=0;j<4;++j) acc[i][j] = (f32x4){0.f,0.f,0.f,0.f};

    const int m0 = blockIdx.y*128, n0 = blockIdx.x*128;
    gemm_main<true>(Xbf, DIM, Wh, Wl, DIM, DIM, m0, n0, sA, sBh, sBl, acc);

    const int t = threadIdx.x, w = t>>6, L = t&63;
    const int wm = 64*(w>>1), wn = 64*(w&1);
    const int cl = L&15, rq = (L>>4)*4;
    #pragma unroll
    for (int nt = 0; nt < 4; ++nt) {
        int col = n0 + wn + nt*16 + cl;
        float bc = bias[col];
        int reg = col >> 10, d = col & (DIM-1);
        #pragma unroll
        for (int mt = 0; mt < 4; ++mt) {
            int row0 = m0 + wm + mt*16 + rq;
            int bi = row0 >> 12, s0 = row0 & (SEQ-1);
            if (reg == 0) {
                #pragma unroll
                for (int r = 0; r < 4; ++r) {
                    size_t idx = ((size_t)bi*SEQ + s0 + r)*DIM + d;
                    Qh[idx] = f2bf(acc[mt][nt][r] + bc);
                }
            } else if (reg == 1) {
                #pragma unroll
                for (int r = 0; r < 4; ++r) {
                    u16 h,l; split2(acc[mt][nt][r] + bc, h, l);
                    size_t idx = ((size_t)bi*SEQ + s0 + r)*DIM + d;
                    Kh[idx] = h; Kl[idx] = l;
                }
            } else {
                ushort4 hv;
                hv.x = f2bf(acc[mt][nt][0] + bc);
                hv.y = f2bf(acc[mt][nt][1] + bc);
                hv.z = f2bf(acc[mt][nt][2] + bc);
                hv.w = f2bf(acc[mt][nt][3] + bc);
                size_t base = ((size_t)bi*DIM + d)*SEQ + s0;
                *(ushort4*)&Vth[base] = hv;
            }
        }
    }
}

// ---------------------------------------------------------------------------
// Scores (per batch): S = scale * Qh @ (Kh+Kl)^T   (2 terms) -> ws (fp32)
// ---------------------------------------------------------------------------
__global__ __launch_bounds__(256,3)
void gemm_scores(const u16* __restrict__ Qh,
                 const u16* __restrict__ Kh, const u16* __restrict__ Kl,
                 float* __restrict__ S)
{
    __shared__ __align__(16) u16 sA[4096], sBh[4096], sBl[4096];
    f32x4 acc[4][4];
    #pragma unroll
    for (int i=0;i<4;++i)
        #pragma unroll
        for (int j=0;j<4;++j) acc[i][j] = (f32x4){0.f,0.f,0.f,0.f};

    const int m0 = blockIdx.y*128, n0 = blockIdx.x*128;
    gemm_main<true>(Qh, DIM, Kh, Kl, DIM, DIM, m0, n0, sA, sBh, sBl, acc);

    const int t = threadIdx.x, w = t>>6, L = t&63;
    const int wm = 64*(w>>1), wn = 64*(w&1);
    const int cl = L&15, rq = (L>>4)*4;
    const float scale = 0.03125f;
    #pragma unroll
    for (int nt = 0; nt < 4; ++nt) {
        int col = n0 + wn + nt*16 + cl;
        #pragma unroll
        for (int mt = 0; mt < 4; ++mt) {
            int row0 = m0 + wm + mt*16 + rq;
            #pragma unroll
            for (int r = 0; r < 4; ++r)
                S[(size_t)(row0 + r)*SEQ + col] = acc[mt][nt][r]*scale;
        }
    }
}

// ---------------------------------------------------------------------------
// Row softmax; P = softmax(S) stored bf16 into the FIRST HALF of the same
// row's slot (u16[0..4095] of the 16KB row) — in-place, race-free per row.
// ---------------------------------------------------------------------------
__global__ __launch_bounds__(256)
void softmax_pack(float* __restrict__ S)
{
    __shared__ float red[4];
    const int t = threadIdx.x, L = t & 63, w = t >> 6;
    float* Srow = S + (size_t)blockIdx.x*SEQ;

    float v[16];
    float m = -1e30f;
    #pragma unroll
    for (int j = 0; j < 4; ++j) {
        float4 x = *(const float4*)&Srow[t*4 + j*1024];
        v[4*j+0]=x.x; v[4*j+1]=x.y; v[4*j+2]=x.z; v[4*j+3]=x.w;
        m = fmaxf(m, fmaxf(fmaxf(x.x,x.y), fmaxf(x.z,x.w)));
    }
    #pragma unroll
    for (int off = 32; off; off >>= 1) m = fmaxf(m, __shfl_xor(m, off, 64));
    if (L == 0) red[w] = m;
    __syncthreads();
    m = fmaxf(fmaxf(red[0],red[1]), fmaxf(red[2],red[3]));

    float s = 0.f;
    #pragma unroll
    for (int i = 0; i < 16; ++i) { v[i] = __expf(v[i] - m); s += v[i]; }
    #pragma unroll
    for (int off = 32; off; off >>= 1) s += __shfl_xor(s, off, 64);
    __syncthreads();
    if (L == 0) red[w] = s;
    __syncthreads();
    s = red[0]+red[1]+red[2]+red[3];
    const float inv = 1.0f / s;

    u16* P = (u16*)Srow;
    #pragma unroll
    for (int j = 0; j < 4; ++j) {
        ushort4 h;
        h.x = f2bf(v[4*j+0]*inv);
        h.y = f2bf(v[4*j+1]*inv);
        h.z = f2bf(v[4*j+2]*inv);
        h.w = f2bf(v[4*j+3]*inv);
        *(ushort4*)&P[t*4 + j*1024] = h;
    }
}

// ---------------------------------------------------------------------------
// PV (per batch): O = P @ Vt^T, single bf16 term, writes d_out directly.
// A = P rows in padded slots (stride 8192 u16); B = Vt[d][s] (stride SEQ).
// ---------------------------------------------------------------------------
__global__ __launch_bounds__(256,3)
void gemm_pv(const u16* __restrict__ P,
             const u16* __restrict__ Vth,
             float* __restrict__ O)
{
    __shared__ __align__(16) u16 sA[4096], sBh[4096];
    f32x4 acc[4][4];
    #pragma unroll
    for (int i=0;i<4;++i)
        #pragma unroll
        for (int j=0;j<4;++j) acc[i][j] = (f32x4){0.f,0.f,0.f,0.f};

    const int m0 = blockIdx.y*128, n0 = blockIdx.x*128;
    gemm_main<false>(P, 2*SEQ, Vth, nullptr, SEQ, SEQ, m0, n0, sA, sBh, nullptr, acc);

    const int t = threadIdx.x, w = t>>6, L = t&63;
    const int wm = 64*(w>>1), wn = 64*(w&1);
    const int cl = L&15, rq = (L>>4)*4;
    #pragma unroll
    for (int nt = 0; nt < 4; ++nt) {
        int col = n0 + wn + nt*16 + cl;
        #pragma unroll
        for (int mt = 0; mt < 4; ++mt) {
            int row0 = m0 + wm + mt*16 + rq;
            #pragma unroll
            for (int r = 0; r < 4; ++r)
                O[(size_t)(row0 + r)*DIM + col] = acc[mt][nt][r];
        }
    }
}

// ---------------------------------------------------------------------------
extern "C" void kernel_launch(void* const* d_in, const int* in_sizes, int n_in,
                              void* d_out, int out_size, void* d_ws, size_t ws_size,
                              hipStream_t stream) {
    const float* X    = (const float*)d_in[0];
    const float* W    = (const float*)d_in[1];
    const float* bias = (const float*)d_in[2];
    float* out = (float*)d_out;

    const size_t MB = (size_t)1 << 20;
    if (ws_size < 192*MB) return;
    char* ws = (char*)d_ws;
    // ws (192 MB): Qh(32) Kh(32) Kl(32) Vth(32) S(64)
    u16*  Qh  = (u16*)ws;
    u16*  Kh  = (u16*)(ws + 32*MB);
    u16*  Kl  = (u16*)(ws + 64*MB);
    u16*  Vth = (u16*)(ws + 96*MB);
    float* S  = (float*)(ws + 128*MB);
    // d_out doubles as pre-attention scratch: Wh(6) Wl(6) pad Xbf(32)
    u16*  Wh  = (u16*)d_out;
    u16*  Wl  = (u16*)((char*)d_out + 6*MB);
    u16*  Xbf = (u16*)((char*)d_out + 16*MB);

    split_f32<<<E3*DIM/1024,   256, 0, stream>>>(W, Wh, Wl);
    cvt_bf16 <<<MTOT*DIM/1024, 256, 0, stream>>>(X, Xbf);

    gemm_qkv<<<dim3(E3/128, MTOT/128), 256, 0, stream>>>(
        Xbf, Wh, Wl, bias, Qh, Kh, Kl, Vth);

    for (int b = 0; b < BATCH; ++b) {
        const size_t qo = (size_t)b*SEQ*DIM;
        gemm_scores<<<dim3(SEQ/128, SEQ/128), 256, 0, stream>>>(
            Qh + qo, Kh + qo, Kl + qo, S);
        softmax_pack<<<SEQ, 256, 0, stream>>>(S);
        gemm_pv<<<dim3(DIM/128, SEQ/128), 256, 0, stream>>>(
            (const u16*)S, Vth + qo, out + qo);
    }
}

// Round 5
// 1054.663 us; speedup vs baseline: 9.9155x; 1.2232x over previous
//
#include <hip/hip_runtime.h>
#include <cstdint>

typedef unsigned short u16;
typedef __attribute__((ext_vector_type(8))) short bf16x8;
typedef __attribute__((ext_vector_type(4))) float f32x4;

#define DIM   1024
#define BATCH 4
#define SEQ   4096
#define E3    3072
#define MTOT  (BATCH*SEQ)   // 16384

// ---------- bf16 helpers (RNE) ----------
__device__ __forceinline__ u16 f2bf(float x) {
    union { float f; unsigned u; } v; v.f = x;
    unsigned r = v.u + 0x7FFFu + ((v.u >> 16) & 1u);
    return (u16)(r >> 16);
}

// ---------- async global->LDS 16B ----------
__device__ __forceinline__ void gl16(const void* g, void* l) {
    __builtin_amdgcn_global_load_lds(
        (const __attribute__((address_space(1))) void*)g,
        (__attribute__((address_space(3))) void*)l, 16, 0, 0);
}

// ---------------------------------------------------------------------------
// GEMM mainloop: C[128x128] += A * B^T, both bf16 k-major, K mult of 32.
// 256 thr = 4 waves 2x2; wave = 4x4 MFMA 16x16x32 tiles.
// LDS fragment-identity chunks: lane L <-> (row L&15, kq L>>4), 16B each.
// ---------------------------------------------------------------------------
__device__ __forceinline__ void gemm_main(
    const u16* __restrict__ A, int sA,
    const u16* __restrict__ B, int sB,
    int K, int m0, int n0,
    u16* sAs, u16* sBs,
    f32x4 acc[4][4])
{
    const int t  = threadIdx.x;
    const int w  = t >> 6, L = t & 63;
    const int rL = L & 15, kq = L >> 4;
    const int c0 = 2*w;

    const size_t a0 = (size_t)(m0 + c0*16 + rL)*sA + kq*8;
    const size_t a1 = a0 + (size_t)16*sA;
    const size_t b0 = (size_t)(n0 + c0*16 + rL)*sB + kq*8;
    const size_t b1 = b0 + (size_t)16*sB;
    u16* lA0 = sAs + c0*512; u16* lA1 = lA0 + 512;
    u16* lB0 = sBs + c0*512; u16* lB1 = lB0 + 512;

    const int cm = 4*(w>>1), cn = 4*(w&1);

    for (int k0 = 0; k0 < K; k0 += 32) {
        __syncthreads();
        gl16(A + a0 + k0, lA0); gl16(A + a1 + k0, lA1);
        gl16(B + b0 + k0, lB0); gl16(B + b1 + k0, lB1);
        __syncthreads();

        bf16x8 av[4], bv[4];
        #pragma unroll
        for (int i = 0; i < 4; ++i) {
            av[i] = *(const bf16x8*)&sAs[(cm+i)*512 + L*8];
            bv[i] = *(const bf16x8*)&sBs[(cn+i)*512 + L*8];
        }
        #pragma unroll
        for (int mt = 0; mt < 4; ++mt)
            #pragma unroll
            for (int nt = 0; nt < 4; ++nt)
                acc[mt][nt] = __builtin_amdgcn_mfma_f32_16x16x32_bf16(av[mt], bv[nt], acc[mt][nt], 0,0,0);
    }
}

// ---------------------------------------------------------------------------
// elementwise: fp32 -> bf16
// ---------------------------------------------------------------------------
__global__ __launch_bounds__(256)
void cvt_bf16(const float* __restrict__ x, u16* __restrict__ y) {
    size_t i = ((size_t)blockIdx.x*256 + threadIdx.x)*4;
    float4 v = *(const float4*)&x[i];
    ushort4 h;
    h.x = f2bf(v.x); h.y = f2bf(v.y); h.z = f2bf(v.z); h.w = f2bf(v.w);
    *(ushort4*)&y[i] = h;
}

// ---------------------------------------------------------------------------
// QKV GEMM: A = Xbf, B = Wbf (1 term). Epilogue:
//   e in [0,1024)    -> Qh[b][s][d] bf16, PRE-SCALED by 1/32
//   e in [1024,2048) -> Kh[b][s][d] bf16
//   e in [2048,3072) -> Vth[b][d][s] bf16 (transposed)
// ---------------------------------------------------------------------------
__global__ __launch_bounds__(256,4)
void gemm_qkv(const u16* __restrict__ Xbf, const u16* __restrict__ Wbf,
              const float* __restrict__ bias,
              u16* __restrict__ Qh, u16* __restrict__ Kh,
              u16* __restrict__ Vth)
{
    __shared__ __align__(16) u16 sA[4096], sB[4096];
    f32x4 acc[4][4];
    #pragma unroll
    for (int i=0;i<4;++i)
        #pragma unroll
        for (int j=0;j<4;++j) acc[i][j] = (f32x4){0.f,0.f,0.f,0.f};

    const int m0 = blockIdx.y*128, n0 = blockIdx.x*128;
    gemm_main(Xbf, DIM, Wbf, DIM, DIM, m0, n0, sA, sB, acc);

    const int t = threadIdx.x, w = t>>6, L = t&63;
    const int wm = 64*(w>>1), wn = 64*(w&1);
    const int cl = L&15, rq = (L>>4)*4;
    const float qscale = 0.03125f;
    #pragma unroll
    for (int nt = 0; nt < 4; ++nt) {
        int col = n0 + wn + nt*16 + cl;
        float bc = bias[col];
        int reg = col >> 10, d = col & (DIM-1);
        #pragma unroll
        for (int mt = 0; mt < 4; ++mt) {
            int row0 = m0 + wm + mt*16 + rq;
            int bi = row0 >> 12, s0 = row0 & (SEQ-1);
            if (reg == 0) {
                #pragma unroll
                for (int r = 0; r < 4; ++r) {
                    size_t idx = ((size_t)bi*SEQ + s0 + r)*DIM + d;
                    Qh[idx] = f2bf((acc[mt][nt][r] + bc)*qscale);
                }
            } else if (reg == 1) {
                #pragma unroll
                for (int r = 0; r < 4; ++r) {
                    size_t idx = ((size_t)bi*SEQ + s0 + r)*DIM + d;
                    Kh[idx] = f2bf(acc[mt][nt][r] + bc);
                }
            } else {
                ushort4 hv;
                hv.x = f2bf(acc[mt][nt][0] + bc);
                hv.y = f2bf(acc[mt][nt][1] + bc);
                hv.z = f2bf(acc[mt][nt][2] + bc);
                hv.w = f2bf(acc[mt][nt][3] + bc);
                size_t base = ((size_t)bi*DIM + d)*SEQ + s0;
                *(ushort4*)&Vth[base] = hv;
            }
        }
    }
}

// ---------------------------------------------------------------------------
// Scores (per batch): S = Qscaled @ Kh^T  -> bf16 S rows (stride SEQ u16)
// ---------------------------------------------------------------------------
__global__ __launch_bounds__(256,4)
void gemm_scores(const u16* __restrict__ Qh, const u16* __restrict__ Kh,
                 u16* __restrict__ S)
{
    __shared__ __align__(16) u16 sA[4096], sB[4096];
    f32x4 acc[4][4];
    #pragma unroll
    for (int i=0;i<4;++i)
        #pragma unroll
        for (int j=0;j<4;++j) acc[i][j] = (f32x4){0.f,0.f,0.f,0.f};

    const int m0 = blockIdx.y*128, n0 = blockIdx.x*128;
    gemm_main(Qh, DIM, Kh, DIM, DIM, m0, n0, sA, sB, acc);

    const int t = threadIdx.x, w = t>>6, L = t&63;
    const int wm = 64*(w>>1), wn = 64*(w&1);
    const int cl = L&15, rq = (L>>4)*4;
    #pragma unroll
    for (int nt = 0; nt < 4; ++nt) {
        int col = n0 + wn + nt*16 + cl;
        #pragma unroll
        for (int mt = 0; mt < 4; ++mt) {
            int row0 = m0 + wm + mt*16 + rq;
            #pragma unroll
            for (int r = 0; r < 4; ++r)
                S[(size_t)(row0 + r)*SEQ + col] = f2bf(acc[mt][nt][r]);
        }
    }
}

// ---------------------------------------------------------------------------
// Row softmax over bf16 S (already scaled), P bf16 written in place.
// ---------------------------------------------------------------------------
__global__ __launch_bounds__(256)
void softmax_pack(u16* __restrict__ S)
{
    __shared__ float red[4];
    const int t = threadIdx.x, L = t & 63, w = t >> 6;
    u16* row = S + (size_t)blockIdx.x*SEQ;

    float v[16];
    float m = -1e30f;
    #pragma unroll
    for (int j = 0; j < 2; ++j) {
        ushort4 x0 = *(const ushort4*)&row[t*8 + j*2048];
        ushort4 x1 = *(const ushort4*)&row[t*8 + j*2048 + 4];
        union { unsigned u; float f; } c;
        c.u = (unsigned)x0.x << 16; v[8*j+0] = c.f;
        c.u = (unsigned)x0.y << 16; v[8*j+1] = c.f;
        c.u = (unsigned)x0.z << 16; v[8*j+2] = c.f;
        c.u = (unsigned)x0.w << 16; v[8*j+3] = c.f;
        c.u = (unsigned)x1.x << 16; v[8*j+4] = c.f;
        c.u = (unsigned)x1.y << 16; v[8*j+5] = c.f;
        c.u = (unsigned)x1.z << 16; v[8*j+6] = c.f;
        c.u = (unsigned)x1.w << 16; v[8*j+7] = c.f;
    }
    #pragma unroll
    for (int i = 0; i < 16; ++i) m = fmaxf(m, v[i]);
    #pragma unroll
    for (int off = 32; off; off >>= 1) m = fmaxf(m, __shfl_xor(m, off, 64));
    if (L == 0) red[w] = m;
    __syncthreads();
    m = fmaxf(fmaxf(red[0],red[1]), fmaxf(red[2],red[3]));

    float s = 0.f;
    #pragma unroll
    for (int i = 0; i < 16; ++i) { v[i] = __expf(v[i] - m); s += v[i]; }
    #pragma unroll
    for (int off = 32; off; off >>= 1) s += __shfl_xor(s, off, 64);
    __syncthreads();
    if (L == 0) red[w] = s;
    __syncthreads();
    s = red[0]+red[1]+red[2]+red[3];
    const float inv = 1.0f / s;

    #pragma unroll
    for (int j = 0; j < 2; ++j) {
        ushort4 h0, h1;
        h0.x = f2bf(v[8*j+0]*inv); h0.y = f2bf(v[8*j+1]*inv);
        h0.z = f2bf(v[8*j+2]*inv); h0.w = f2bf(v[8*j+3]*inv);
        h1.x = f2bf(v[8*j+4]*inv); h1.y = f2bf(v[8*j+5]*inv);
        h1.z = f2bf(v[8*j+6]*inv); h1.w = f2bf(v[8*j+7]*inv);
        *(ushort4*)&row[t*8 + j*2048]     = h0;
        *(ushort4*)&row[t*8 + j*2048 + 4] = h1;
    }
}

// ---------------------------------------------------------------------------
// PV (per batch): O = P @ Vt^T -> d_out fp32. A stride SEQ, B stride SEQ.
// ---------------------------------------------------------------------------
__global__ __launch_bounds__(256,4)
void gemm_pv(const u16* __restrict__ P, const u16* __restrict__ Vth,
             float* __restrict__ O)
{
    __shared__ __align__(16) u16 sA[4096], sB[4096];
    f32x4 acc[4][4];
    #pragma unroll
    for (int i=0;i<4;++i)
        #pragma unroll
        for (int j=0;j<4;++j) acc[i][j] = (f32x4){0.f,0.f,0.f,0.f};

    const int m0 = blockIdx.y*128, n0 = blockIdx.x*128;
    gemm_main(P, SEQ, Vth, SEQ, SEQ, m0, n0, sA, sB, acc);

    const int t = threadIdx.x, w = t>>6, L = t&63;
    const int wm = 64*(w>>1), wn = 64*(w&1);
    const int cl = L&15, rq = (L>>4)*4;
    #pragma unroll
    for (int nt = 0; nt < 4; ++nt) {
        int col = n0 + wn + nt*16 + cl;
        #pragma unroll
        for (int mt = 0; mt < 4; ++mt) {
            int row0 = m0 + wm + mt*16 + rq;
            #pragma unroll
            for (int r = 0; r < 4; ++r)
                O[(size_t)(row0 + r)*DIM + col] = acc[mt][nt][r];
        }
    }
}

// ---------------------------------------------------------------------------
extern "C" void kernel_launch(void* const* d_in, const int* in_sizes, int n_in,
                              void* d_out, int out_size, void* d_ws, size_t ws_size,
                              hipStream_t stream) {
    const float* X    = (const float*)d_in[0];
    const float* W    = (const float*)d_in[1];
    const float* bias = (const float*)d_in[2];
    float* out = (float*)d_out;

    const size_t MB = (size_t)1 << 20;
    if (ws_size < 192*MB) return;
    char* ws = (char*)d_ws;
    // ws: Qh(32) Kh(32) Vth(32) S(32, per-batch reuse) Xbf(32) Wbf(6)
    u16* Qh  = (u16*)ws;
    u16* Kh  = (u16*)(ws + 32*MB);
    u16* Vth = (u16*)(ws + 64*MB);
    u16* S   = (u16*)(ws + 96*MB);
    u16* Xbf = (u16*)(ws + 128*MB);
    u16* Wbf = (u16*)(ws + 160*MB);

    cvt_bf16<<<MTOT*DIM/1024, 256, 0, stream>>>(X, Xbf);
    cvt_bf16<<<E3*DIM/1024,   256, 0, stream>>>(W, Wbf);

    gemm_qkv<<<dim3(E3/128, MTOT/128), 256, 0, stream>>>(
        Xbf, Wbf, bias, Qh, Kh, Vth);

    for (int b = 0; b < BATCH; ++b) {
        const size_t qo = (size_t)b*SEQ*DIM;
        gemm_scores<<<dim3(SEQ/128, SEQ/128), 256, 0, stream>>>(
            Qh + qo, Kh + qo, S);
        softmax_pack<<<SEQ, 256, 0, stream>>>(S);
        gemm_pv<<<dim3(DIM/128, SEQ/128), 256, 0, stream>>>(
            S, Vth + qo, out + qo);
    }
}

// Round 6
// 864.839 us; speedup vs baseline: 12.0918x; 1.2195x over previous
//
#include <hip/hip_runtime.h>
#include <cstdint>

typedef unsigned short u16;
typedef __attribute__((ext_vector_type(8))) short bf16x8;
typedef __attribute__((ext_vector_type(4))) float f32x4;

#define DIM   1024
#define BATCH 4
#define SEQ   4096
#define E3    3072
#define MTOT  (BATCH*SEQ)   // 16384

// ---------- bf16 helpers (RNE) ----------
__device__ __forceinline__ u16 f2bf(float x) {
    union { float f; unsigned u; } v; v.f = x;
    unsigned r = v.u + 0x7FFFu + ((v.u >> 16) & 1u);
    return (u16)(r >> 16);
}

// ---------- async global->LDS 16B ----------
__device__ __forceinline__ void gl16(const void* g, void* l) {
    __builtin_amdgcn_global_load_lds(
        (const __attribute__((address_space(1))) void*)g,
        (__attribute__((address_space(3))) void*)l, 16, 0, 0);
}

// ---------------------------------------------------------------------------
// GEMM mainloop: C[128x128] += A * B^T, both bf16 k-major, K mult of 32.
// 256 thr = 4 waves 2x2; wave = 4x4 MFMA 16x16x32 tiles.
// LDS fragment-identity chunks: lane L <-> (row L&15, kq L>>4), 16B each.
// ---------------------------------------------------------------------------
__device__ __forceinline__ void gemm_main(
    const u16* __restrict__ A, int sA,
    const u16* __restrict__ B, int sB,
    int K, int m0, int n0,
    u16* sAs, u16* sBs,
    f32x4 acc[4][4])
{
    const int t  = threadIdx.x;
    const int w  = t >> 6, L = t & 63;
    const int rL = L & 15, kq = L >> 4;
    const int c0 = 2*w;

    const size_t a0 = (size_t)(m0 + c0*16 + rL)*sA + kq*8;
    const size_t a1 = a0 + (size_t)16*sA;
    const size_t b0 = (size_t)(n0 + c0*16 + rL)*sB + kq*8;
    const size_t b1 = b0 + (size_t)16*sB;
    u16* lA0 = sAs + c0*512; u16* lA1 = lA0 + 512;
    u16* lB0 = sBs + c0*512; u16* lB1 = lB0 + 512;

    const int cm = 4*(w>>1), cn = 4*(w&1);

    for (int k0 = 0; k0 < K; k0 += 32) {
        __syncthreads();
        gl16(A + a0 + k0, lA0); gl16(A + a1 + k0, lA1);
        gl16(B + b0 + k0, lB0); gl16(B + b1 + k0, lB1);
        __syncthreads();

        bf16x8 av[4], bv[4];
        #pragma unroll
        for (int i = 0; i < 4; ++i) {
            av[i] = *(const bf16x8*)&sAs[(cm+i)*512 + L*8];
            bv[i] = *(const bf16x8*)&sBs[(cn+i)*512 + L*8];
        }
        #pragma unroll
        for (int mt = 0; mt < 4; ++mt)
            #pragma unroll
            for (int nt = 0; nt < 4; ++nt)
                acc[mt][nt] = __builtin_amdgcn_mfma_f32_16x16x32_bf16(av[mt], bv[nt], acc[mt][nt], 0,0,0);
    }
}

// ---------------------------------------------------------------------------
// elementwise: fp32 -> bf16
// ---------------------------------------------------------------------------
__global__ __launch_bounds__(256)
void cvt_bf16(const float* __restrict__ x, u16* __restrict__ y) {
    size_t i = ((size_t)blockIdx.x*256 + threadIdx.x)*4;
    float4 v = *(const float4*)&x[i];
    ushort4 h;
    h.x = f2bf(v.x); h.y = f2bf(v.y); h.z = f2bf(v.z); h.w = f2bf(v.w);
    *(ushort4*)&y[i] = h;
}

// ---------------------------------------------------------------------------
// QKV GEMM: A = Xbf, B = Wbf. Epilogue:
//   Q region: pre-scaled by 1/32, bf16, row-major  (pair-packed u32 stores)
//   K region: bf16, row-major                      (pair-packed u32 stores)
//   V region: bf16, transposed [b][d][s]           (ushort4 stores, merge ok)
// Pair-packing: lanes cl^1 exchange final values via shfl; even lane stores
// cols (nt0*16+cl, +1), odd lane stores cols (nt1*16+cl-1, cl) -> 16 lanes
// cover 64B contiguous = full cache lines.
// ---------------------------------------------------------------------------
__global__ __launch_bounds__(256,4)
void gemm_qkv(const u16* __restrict__ Xbf, const u16* __restrict__ Wbf,
              const float* __restrict__ bias,
              u16* __restrict__ Qh, u16* __restrict__ Kh,
              u16* __restrict__ Vth)
{
    __shared__ __align__(16) u16 sA[4096], sB[4096];
    f32x4 acc[4][4];
    #pragma unroll
    for (int i=0;i<4;++i)
        #pragma unroll
        for (int j=0;j<4;++j) acc[i][j] = (f32x4){0.f,0.f,0.f,0.f};

    const int m0 = blockIdx.y*128, n0 = blockIdx.x*128;
    gemm_main(Xbf, DIM, Wbf, DIM, DIM, m0, n0, sA, sB, acc);

    const int t = threadIdx.x, w = t>>6, L = t&63;
    const int wm = 64*(w>>1), wn = 64*(w&1);
    const int cl = L&15, rq = (L>>4)*4;
    const int region = n0 >> 10;           // whole block in one region
    const float qscale = 0.03125f;

    if (region < 2) {
        u16* Dst = region ? Kh : Qh;
        const float fs = region ? 1.0f : qscale;
        // add bias (+scale for Q) in place
        #pragma unroll
        for (int nt = 0; nt < 4; ++nt) {
            float bc = bias[n0 + wn + nt*16 + cl];
            #pragma unroll
            for (int mt = 0; mt < 4; ++mt)
                #pragma unroll
                for (int r = 0; r < 4; ++r)
                    acc[mt][nt][r] = (acc[mt][nt][r] + bc)*fs;
        }
        const int d0 = (n0 & 1023) + wn;
        #pragma unroll
        for (int p = 0; p < 2; ++p) {
            const int nt0 = 2*p, nt1 = 2*p+1;
            #pragma unroll
            for (int mt = 0; mt < 4; ++mt) {
                int row0 = m0 + wm + mt*16 + rq;
                int bi = row0 >> 12, s0 = row0 & (SEQ-1);
                #pragma unroll
                for (int r = 0; r < 4; ++r) {
                    float v0 = acc[mt][nt0][r], v1 = acc[mt][nt1][r];
                    float x0 = __shfl_xor(v0, 1, 64);
                    float x1 = __shfl_xor(v1, 1, 64);
                    unsigned wv; int colb;
                    if ((cl & 1) == 0) {
                        wv   = (unsigned)f2bf(v0) | ((unsigned)f2bf(x0) << 16);
                        colb = nt0*16 + cl;
                    } else {
                        wv   = (unsigned)f2bf(x1) | ((unsigned)f2bf(v1) << 16);
                        colb = nt1*16 + (cl-1);
                    }
                    size_t idx = ((size_t)bi*SEQ + s0 + r)*DIM + d0 + colb;
                    *(unsigned*)&Dst[idx] = wv;
                }
            }
        }
    } else {
        #pragma unroll
        for (int nt = 0; nt < 4; ++nt) {
            int col = n0 + wn + nt*16 + cl;
            float bc = bias[col];
            int d = col & (DIM-1);
            #pragma unroll
            for (int mt = 0; mt < 4; ++mt) {
                int row0 = m0 + wm + mt*16 + rq;
                int bi = row0 >> 12, s0 = row0 & (SEQ-1);
                ushort4 hv;
                hv.x = f2bf(acc[mt][nt][0] + bc);
                hv.y = f2bf(acc[mt][nt][1] + bc);
                hv.z = f2bf(acc[mt][nt][2] + bc);
                hv.w = f2bf(acc[mt][nt][3] + bc);
                size_t base = ((size_t)bi*DIM + d)*SEQ + s0;
                *(ushort4*)&Vth[base] = hv;
            }
        }
    }
}

// ---------------------------------------------------------------------------
// Scores, all batches: S_b = Qscaled_b @ K_b^T -> bf16, pair-packed stores.
// ---------------------------------------------------------------------------
__global__ __launch_bounds__(256,4)
void gemm_scores(const u16* __restrict__ Qh, const u16* __restrict__ Kh,
                 u16* __restrict__ S0, u16* __restrict__ S1,
                 u16* __restrict__ S2, u16* __restrict__ S3)
{
    __shared__ __align__(16) u16 sA[4096], sB[4096];
    f32x4 acc[4][4];
    #pragma unroll
    for (int i=0;i<4;++i)
        #pragma unroll
        for (int j=0;j<4;++j) acc[i][j] = (f32x4){0.f,0.f,0.f,0.f};

    const int bz = blockIdx.z;
    const size_t qo = (size_t)bz*SEQ*DIM;
    const int m0 = blockIdx.y*128, n0 = blockIdx.x*128;
    gemm_main(Qh + qo, DIM, Kh + qo, DIM, DIM, m0, n0, sA, sB, acc);

    u16* Sb = (bz == 0) ? S0 : (bz == 1) ? S1 : (bz == 2) ? S2 : S3;
    const int t = threadIdx.x, w = t>>6, L = t&63;
    const int wm = 64*(w>>1), wn = 64*(w&1);
    const int cl = L&15, rq = (L>>4)*4;
    #pragma unroll
    for (int p = 0; p < 2; ++p) {
        const int nt0 = 2*p, nt1 = 2*p+1;
        #pragma unroll
        for (int mt = 0; mt < 4; ++mt) {
            int row0 = m0 + wm + mt*16 + rq;
            #pragma unroll
            for (int r = 0; r < 4; ++r) {
                float v0 = acc[mt][nt0][r], v1 = acc[mt][nt1][r];
                float x0 = __shfl_xor(v0, 1, 64);
                float x1 = __shfl_xor(v1, 1, 64);
                unsigned wv; int colb;
                if ((cl & 1) == 0) {
                    wv   = (unsigned)f2bf(v0) | ((unsigned)f2bf(x0) << 16);
                    colb = nt0*16 + cl;
                } else {
                    wv   = (unsigned)f2bf(x1) | ((unsigned)f2bf(v1) << 16);
                    colb = nt1*16 + (cl-1);
                }
                *(unsigned*)&Sb[(size_t)(row0 + r)*SEQ + n0 + wn + colb] = wv;
            }
        }
    }
}

// ---------------------------------------------------------------------------
// Row softmax over bf16 S (pre-scaled scores), P bf16 in place. 16384 rows.
// ---------------------------------------------------------------------------
__global__ __launch_bounds__(256)
void softmax_pack(u16* __restrict__ S0, u16* __restrict__ S1,
                  u16* __restrict__ S2, u16* __restrict__ S3)
{
    __shared__ float red[4];
    const int t = threadIdx.x, L = t & 63, w = t >> 6;
    const int gr = blockIdx.x, bz = gr >> 12, rr = gr & (SEQ-1);
    u16* Sb = (bz == 0) ? S0 : (bz == 1) ? S1 : (bz == 2) ? S2 : S3;
    u16* row = Sb + (size_t)rr*SEQ;

    float v[16];
    float m = -1e30f;
    #pragma unroll
    for (int j = 0; j < 2; ++j) {
        ushort4 x0 = *(const ushort4*)&row[t*8 + j*2048];
        ushort4 x1 = *(const ushort4*)&row[t*8 + j*2048 + 4];
        union { unsigned u; float f; } c;
        c.u = (unsigned)x0.x << 16; v[8*j+0] = c.f;
        c.u = (unsigned)x0.y << 16; v[8*j+1] = c.f;
        c.u = (unsigned)x0.z << 16; v[8*j+2] = c.f;
        c.u = (unsigned)x0.w << 16; v[8*j+3] = c.f;
        c.u = (unsigned)x1.x << 16; v[8*j+4] = c.f;
        c.u = (unsigned)x1.y << 16; v[8*j+5] = c.f;
        c.u = (unsigned)x1.z << 16; v[8*j+6] = c.f;
        c.u = (unsigned)x1.w << 16; v[8*j+7] = c.f;
    }
    #pragma unroll
    for (int i = 0; i < 16; ++i) m = fmaxf(m, v[i]);
    #pragma unroll
    for (int off = 32; off; off >>= 1) m = fmaxf(m, __shfl_xor(m, off, 64));
    if (L == 0) red[w] = m;
    __syncthreads();
    m = fmaxf(fmaxf(red[0],red[1]), fmaxf(red[2],red[3]));

    float s = 0.f;
    #pragma unroll
    for (int i = 0; i < 16; ++i) { v[i] = __expf(v[i] - m); s += v[i]; }
    #pragma unroll
    for (int off = 32; off; off >>= 1) s += __shfl_xor(s, off, 64);
    __syncthreads();
    if (L == 0) red[w] = s;
    __syncthreads();
    s = red[0]+red[1]+red[2]+red[3];
    const float inv = 1.0f / s;

    #pragma unroll
    for (int j = 0; j < 2; ++j) {
        ushort4 h0, h1;
        h0.x = f2bf(v[8*j+0]*inv); h0.y = f2bf(v[8*j+1]*inv);
        h0.z = f2bf(v[8*j+2]*inv); h0.w = f2bf(v[8*j+3]*inv);
        h1.x = f2bf(v[8*j+4]*inv); h1.y = f2bf(v[8*j+5]*inv);
        h1.z = f2bf(v[8*j+6]*inv); h1.w = f2bf(v[8*j+7]*inv);
        *(ushort4*)&row[t*8 + j*2048]     = h0;
        *(ushort4*)&row[t*8 + j*2048 + 4] = h1;
    }
}

// ---------------------------------------------------------------------------
// PV, all batches: O_b = P_b @ Vt_b^T -> fp32 (scalar stores = full lines)
// ---------------------------------------------------------------------------
__global__ __launch_bounds__(256,4)
void gemm_pv(const u16* __restrict__ P0, const u16* __restrict__ P1,
             const u16* __restrict__ P2, const u16* __restrict__ P3,
             const u16* __restrict__ Vth,
             float* __restrict__ O0, float* __restrict__ O1,
             float* __restrict__ O2, float* __restrict__ O3)
{
    __shared__ __align__(16) u16 sA[4096], sB[4096];
    f32x4 acc[4][4];
    #pragma unroll
    for (int i=0;i<4;++i)
        #pragma unroll
        for (int j=0;j<4;++j) acc[i][j] = (f32x4){0.f,0.f,0.f,0.f};

    const int bz = blockIdx.z;
    const u16* Pb = (bz == 0) ? P0 : (bz == 1) ? P1 : (bz == 2) ? P2 : P3;
    float*     Ob = (bz == 0) ? O0 : (bz == 1) ? O1 : (bz == 2) ? O2 : O3;
    const int m0 = blockIdx.y*128, n0 = blockIdx.x*128;
    gemm_main(Pb, SEQ, Vth + (size_t)bz*DIM*SEQ, SEQ, SEQ, m0, n0, sA, sB, acc);

    const int t = threadIdx.x, w = t>>6, L = t&63;
    const int wm = 64*(w>>1), wn = 64*(w&1);
    const int cl = L&15, rq = (L>>4)*4;
    #pragma unroll
    for (int nt = 0; nt < 4; ++nt) {
        int col = n0 + wn + nt*16 + cl;
        #pragma unroll
        for (int mt = 0; mt < 4; ++mt) {
            int row0 = m0 + wm + mt*16 + rq;
            #pragma unroll
            for (int r = 0; r < 4; ++r)
                Ob[(size_t)(row0 + r)*DIM + col] = acc[mt][nt][r];
        }
    }
}

// ---------------------------------------------------------------------------
// linear copy (float4), for O2/O3 parked in ws -> d_out second half
// ---------------------------------------------------------------------------
__global__ __launch_bounds__(256)
void copy_out(const float* __restrict__ src, float* __restrict__ dst)
{
    size_t i = ((size_t)blockIdx.x*256 + threadIdx.x)*4;
    *(float4*)&dst[i] = *(const float4*)&src[i];
}

// ---------------------------------------------------------------------------
extern "C" void kernel_launch(void* const* d_in, const int* in_sizes, int n_in,
                              void* d_out, int out_size, void* d_ws, size_t ws_size,
                              hipStream_t stream) {
    const float* X    = (const float*)d_in[0];
    const float* W    = (const float*)d_in[1];
    const float* bias = (const float*)d_in[2];
    float* out = (float*)d_out;

    const size_t MB = (size_t)1 << 20;
    if (ws_size < 192*MB) return;
    char* ws = (char*)d_ws;
    char* wo = (char*)d_out;
    // ws: Qh[0,32) Kh[32,64) Vth[64,96) S0[96,128) S1[128,160) S2[160,192)
    u16* Qh  = (u16*)ws;
    u16* Kh  = (u16*)(ws + 32*MB);
    u16* Vth = (u16*)(ws + 64*MB);
    u16* S0  = (u16*)(ws + 96*MB);
    u16* S1  = (u16*)(ws + 128*MB);
    u16* S2  = (u16*)(ws + 160*MB);
    // d_out during prologue: Xbf[0,32) Wbf[32,38); during attention: S3[32,64)
    u16* Xbf = (u16*)wo;
    u16* Wbf = (u16*)(wo + 32*MB);
    u16* S3  = (u16*)(wo + 32*MB);
    // pv outputs: O0,O1 -> d_out[0,32); O2,O3 -> dead Qh/Kh-front ws[0,32)
    float* O0 = (float*)wo;
    float* O1 = (float*)(wo + 16*MB);
    float* O2 = (float*)ws;
    float* O3 = (float*)(ws + 16*MB);

    cvt_bf16<<<MTOT*DIM/1024, 256, 0, stream>>>(X, Xbf);
    cvt_bf16<<<E3*DIM/1024,   256, 0, stream>>>(W, Wbf);

    gemm_qkv<<<dim3(E3/128, MTOT/128), 256, 0, stream>>>(
        Xbf, Wbf, bias, Qh, Kh, Vth);

    gemm_scores<<<dim3(SEQ/128, SEQ/128, BATCH), 256, 0, stream>>>(
        Qh, Kh, S0, S1, S2, S3);

    softmax_pack<<<MTOT, 256, 0, stream>>>(S0, S1, S2, S3);

    gemm_pv<<<dim3(DIM/128, SEQ/128, BATCH), 256, 0, stream>>>(
        S0, S1, S2, S3, Vth, O0, O1, O2, O3);

    // O2,O3 (32 MB in ws) -> d_out[32,64)
    copy_out<<<(32*MB/sizeof(float))/1024, 256, 0, stream>>>(
        (const float*)ws, out + 8*MB);   // 8M floats = 32 MB offset
}